// Round 5
// baseline (537.169 us; speedup 1.0000x reference)
//
#include <hip/hip_runtime.h>

// Fused FSAS: conv1x1(48->288, MFMA) -> depthwise3x3 -> per-64px-segment 8x8
// circular conv (fp32 VALU, conflict-free q-broadcast) -> LayerNorm(96ch) ->
// v*normed -> conv1x1(96->48, K-split MFMA accumulate).
// Software-pipelined: {B1(c+1) || B3(c)} sync {B2(c+1)} sync; v-loop uses
// double-buffered hid + alternating avp buffers. Block=(wseg,h,b), 3 blk/CU.
//
// R5 fix: MFMAacc quad-3 lanes read avp[(p+1)*24+0..7]; for p=63 that is 16 B
// past the buffer. avpA's tail lands on stale fp32 qs data, whose low 16 bits
// can decode as bf16 NaN/Inf -> 0*NaN = NaN in the MFMA accumulator (R4's
// failure). We zero that tail once before the v-loop. avpB's tail lands on
// osh row 24 (always finite bf16) - safe by construction.

#define B_ 4
#define C_ 48
#define H_ 256
#define W_ 256
#define ROWS 68        // halo row width (66 valid)
#define NPX 208        // 13 n-tiles of 16
#define XT_STR 52      // xs_t ushort stride (26 dwords: ~2-way max)
#define HROW 72        // hid inner row stride (16B-aligned b128 windows)
#define HID_STR 216    // 3*HROW
#define QS_STR 68      // qs fp32 stride

// ---- LDS offsets (bytes) ----
#define OFF_XT  0                  // ushort xs_t[208][52] = 21632
#define OFF_HID 21632              // ushort hid[24][216] = 10368 (v: 2x [12][216])
#define OFF_QS  32000              // float qs[12][68] = 3264 (alias: LN part 2048 / avpA [64][24]u 3072)
#define OFF_KS  35264              // ushort ks[12][64] = 1536
#define OFF_OSH 36800              // ushort osh[96][64] = 12288 (rows 0..23 alias avpB in v-loop)
#define OFF_MU  49088              // float[64]
#define OFF_RS  49344              // float[64]
#define SMEM_BYTES 49600           // 3 blocks/CU (<54613)

typedef __attribute__((ext_vector_type(8))) short short8;
typedef __attribute__((ext_vector_type(4))) float floatx4;
union U128 { unsigned long long u[2]; short8 s; };

__device__ __forceinline__ float bf2f(unsigned short u) {
  return __uint_as_float(((unsigned int)u) << 16);
}
__device__ __forceinline__ unsigned short f2bf(float f) {  // RNE
  unsigned int x = __float_as_uint(f);
  x += 0x7FFFu + ((x >> 16) & 1u);
  return (unsigned short)(x >> 16);
}
__device__ __forceinline__ unsigned long long pack4(float a, float b, float c, float d) {
  return (unsigned long long)f2bf(a) | ((unsigned long long)f2bf(b) << 16) |
         ((unsigned long long)f2bf(c) << 32) | ((unsigned long long)f2bf(d) << 48);
}

// ---- weight prep into d_ws (ushort units) ----
// wqk[8][32][64]: rows 0..11=q(c6=ch*12+m), 12..23=k(96+ch*12+m-12), 24..31=0; k>=48->0
// wv1[8][16][64]: rows 0..11=v(192+ch*12+m), 12..15=0; k>=48->0        (+16384)
// w2p[4][48][32]: [pr][co][kk] = kk<24 ? wo[co*96 + pr*24 + kk] : 0    (+24576)
__global__ void fsas_prep(const float* __restrict__ wh, const float* __restrict__ wo,
                          unsigned short* __restrict__ ws) {
  int idx = blockIdx.x * 256 + threadIdx.x;
  if (idx < 16384) {
    int kk = idx & 63, t = idx >> 6;
    int m = t & 31, ch = t >> 5;
    float v = 0.f;
    if (kk < 48 && m < 24) {
      int c6 = (m < 12) ? (ch * 12 + m) : (96 + ch * 12 + (m - 12));
      v = wh[c6 * 48 + kk];
    }
    ws[idx] = f2bf(v);
  } else if (idx < 24576) {
    int e = idx - 16384;
    int kk = e & 63, t = e >> 6;
    int m = t & 15, ch = t >> 4;
    float v = 0.f;
    if (kk < 48 && m < 12) v = wh[(192 + ch * 12 + m) * 48 + kk];
    ws[idx] = f2bf(v);
  } else {
    int e = idx - 24576;
    int kk = e & 31, t = e >> 5;
    int co = t % 48, pr = t / 48;
    float v = (kk < 24) ? wo[co * 96 + pr * 24 + kk] : 0.f;
    ws[idx] = f2bf(v);
  }
}

__global__ __launch_bounds__(256, 3) void fsas_fused(
    const float* __restrict__ x,   const float* __restrict__ bh,
    const float* __restrict__ wdw, const float* __restrict__ bdw,
    const float* __restrict__ gam, const float* __restrict__ bet,
    const float* __restrict__ bo,  const unsigned short* __restrict__ ws,
    float* __restrict__ y)
{
  __shared__ __align__(16) char smem[SMEM_BYTES];
  unsigned short* xs_t = (unsigned short*)(smem + OFF_XT);
  unsigned short* hid  = (unsigned short*)(smem + OFF_HID);
  float* qs = (float*)(smem + OFF_QS);
  unsigned short* ks  = (unsigned short*)(smem + OFF_KS);
  unsigned short* osh = (unsigned short*)(smem + OFF_OSH);
  float* mu = (float*)(smem + OFF_MU);
  float* rs = (float*)(smem + OFF_RS);
  float2* part = (float2*)(smem + OFF_QS);            // alias (LN partials)
  unsigned short* avpA = (unsigned short*)(smem + OFF_QS);   // alias [64][24]
  unsigned short* avpB = (unsigned short*)(smem + OFF_OSH);  // alias osh rows 0..23

  const unsigned short* wqk = ws;
  const unsigned short* wv1 = ws + 16384;
  const unsigned short* w2p = ws + 24576;

  const int tid  = threadIdx.x;
  const int wseg = blockIdx.x;
  const int h    = blockIdx.y;
  const int b    = blockIdx.z;
  const int w0   = wseg * 64;
  const int lane = tid & 63;
  const int wv   = tid >> 6;
  const int ln   = lane & 15;
  const int quad = lane >> 4;

  // ---- Stage A: x halo -> xs_t[p][c] bf16, coalesced global reads ----
  for (int idx = tid; idx < C_ * NPX; idx += 256) {
    int c = idx / NPX;
    int p = idx - c * NPX;
    int rr = p / ROWS, cc = p - rr * ROWS;
    float val = 0.f;
    if (rr < 3 && cc < 66) {
      int gr = h - 1 + rr, gc = w0 - 1 + cc;
      if (gr >= 0 && gr < H_ && gc >= 0 && gc < W_)
        val = x[(((b * C_) + c) * H_ + gr) * W_ + gc];
    }
    xs_t[p * XT_STR + c] = f2bf(val);
  }
  for (int p = tid; p < NPX; p += 256)                // zero pad channels 48..51
    *(unsigned long long*)(xs_t + p * XT_STR + 48) = 0ull;
  __syncthreads();

  // ---- phase lambdas ----
  auto B1qk = [&](int chunk) {
    short8 aq[2][2];
    #pragma unroll
    for (int mt = 0; mt < 2; ++mt)
      #pragma unroll
      for (int kx = 0; kx < 2; ++kx)
        aq[mt][kx] = *(const short8*)(wqk + ((chunk * 32 + mt * 16 + ln) * 64 + kx * 32 + quad * 8));
    float bqk[2][4];
    #pragma unroll
    for (int mt = 0; mt < 2; ++mt)
      #pragma unroll
      for (int r = 0; r < 4; ++r) {
        int row = mt * 16 + quad * 4 + r;
        float bv = 0.f;
        if (row < 12) bv = bh[chunk * 12 + row];
        else if (row < 24) bv = bh[96 + chunk * 12 + row - 12];
        bqk[mt][r] = bv;
      }
    for (int nt = wv; nt < 13; nt += 4) {
      int p = nt * 16 + ln;
      int rr = p / ROWS, cc = p - rr * ROWS;
      int gr = h - 1 + rr, gc = w0 - 1 + cc;
      bool pv = (rr < 3) && (cc < 66) && (gr >= 0) && (gr < H_) && (gc >= 0) && (gc < W_);
      const unsigned short* bp = xs_t + p * XT_STR + quad * 8;
      U128 b0, b1;
      b0.u[0] = *(const unsigned long long*)(bp);
      b0.u[1] = *(const unsigned long long*)(bp + 4);
      b1.u[0] = *(const unsigned long long*)(bp + 32);  // k>=48 junk * zero-A = 0
      b1.u[1] = *(const unsigned long long*)(bp + 36);  // (junk NaN only reaches discarded rr=3 columns)
      #pragma unroll
      for (int mt = 0; mt < 2; ++mt) {
        floatx4 acc = {bqk[mt][0], bqk[mt][1], bqk[mt][2], bqk[mt][3]};
        acc = __builtin_amdgcn_mfma_f32_16x16x32_bf16(aq[mt][0], b0.s, acc, 0, 0, 0);
        acc = __builtin_amdgcn_mfma_f32_16x16x32_bf16(aq[mt][1], b1.s, acc, 0, 0, 0);
        if (rr < 3) {
          if (mt == 0) {
            #pragma unroll
            for (int r = 0; r < 4; ++r)
              hid[(quad * 4 + r) * HID_STR + rr * HROW + cc] = pv ? f2bf(acc[r]) : (unsigned short)0;
          } else if (quad < 2) {
            #pragma unroll
            for (int r = 0; r < 4; ++r)
              hid[(16 + quad * 4 + r) * HID_STR + rr * HROW + cc] = pv ? f2bf(acc[r]) : (unsigned short)0;
          }
        }
      }
    }
  };

  auto B2qk = [&](int chunk) {
    if (tid < 192) {
      int cl = tid >> 3, pg = tid & 7, p0 = pg * 8;
      int lc = (cl < 12) ? cl : cl - 12;
      int c6 = (cl < 12) ? (chunk * 12 + cl) : (96 + chunk * 12 + lc);
      const float* wd = wdw + c6 * 9;
      float bb = bdw[c6];
      float a8[8];
      #pragma unroll
      for (int t = 0; t < 8; ++t) a8[t] = bb;
      const unsigned short* base = hid + cl * HID_STR + p0;
      #pragma unroll
      for (int di = 0; di < 3; ++di) {
        const unsigned short* hrow = base + di * HROW;
        U128 hv;
        hv.u[0] = *(const unsigned long long*)(hrow);
        hv.u[1] = *(const unsigned long long*)(hrow + 4);
        unsigned int ex = *(const unsigned int*)(hrow + 8);
        float hf[10];
        #pragma unroll
        for (int t = 0; t < 4; ++t) hf[t] = bf2f((unsigned short)(hv.u[0] >> (16 * t)));
        #pragma unroll
        for (int t = 0; t < 4; ++t) hf[4 + t] = bf2f((unsigned short)(hv.u[1] >> (16 * t)));
        hf[8] = bf2f((unsigned short)ex);
        hf[9] = bf2f((unsigned short)(ex >> 16));
        #pragma unroll
        for (int dj = 0; dj < 3; ++dj) {
          float w = wd[di * 3 + dj];
          #pragma unroll
          for (int t = 0; t < 8; ++t) a8[t] += w * hf[t + dj];
        }
      }
      if (cl < 12) {
        float* dst = qs + cl * QS_STR + p0;
        *(float4*)(dst)     = make_float4(a8[0], a8[1], a8[2], a8[3]);
        *(float4*)(dst + 4) = make_float4(a8[4], a8[5], a8[6], a8[7]);
      } else {
        unsigned short* dst = ks + lc * 64 + p0;
        *(unsigned long long*)(dst)     = pack4(a8[0], a8[1], a8[2], a8[3]);
        *(unsigned long long*)(dst + 4) = pack4(a8[4], a8[5], a8[6], a8[7]);
      }
    }
  };

  auto B3 = [&](int chunk) {
    if (tid < 192) {
      int cl = tid >> 4, r4 = tid & 15, uu = r4 >> 1, vh = r4 & 1;
      const float* qrow = qs + cl * QS_STR;
      const unsigned short* krow = ks + cl * 64;
      float a4[4] = {0.f, 0.f, 0.f, 0.f};
      #pragma unroll
      for (int i = 0; i < 8; ++i) {
        // qr[m] = q[i][(m+4*vh)&7]: fold vh-rotation into q load offsets
        float4 qA = *(const float4*)(qrow + i * 8 + vh * 4);
        float4 qB = *(const float4*)(qrow + i * 8 + (vh ^ 1) * 4);
        int ri = (uu - i) & 7;
        short8 kv = *(const short8*)(krow + ri * 8);
        float kf[8];
        #pragma unroll
        for (int j = 0; j < 8; ++j) kf[j] = bf2f((unsigned short)kv[j]);
        float qr[8] = {qA.x, qA.y, qA.z, qA.w, qB.x, qB.y, qB.z, qB.w};
        #pragma unroll
        for (int u = 0; u < 4; ++u)
          #pragma unroll
          for (int m = 0; m < 8; ++m)
            a4[u] += qr[m] * kf[(u - m) & 7];   // compile-time k index
      }
      int c2 = chunk * 12 + cl;
      *(unsigned long long*)(osh + c2 * 64 + uu * 8 + vh * 4) = pack4(a4[0], a4[1], a4[2], a4[3]);
    }
  };

  // ======== pipelined chunk loop: {B1(c+1) || B3(c)} sync {B2(c+1)} sync ====
  B1qk(0);
  __syncthreads();
  B2qk(0);
  __syncthreads();
  for (int c = 0; c < 8; ++c) {
    if (c < 7) B1qk(c + 1);
    B3(c);
    __syncthreads();
    if (c < 7) {
      B2qk(c + 1);
      __syncthreads();
    }
  }

  // ======== LayerNorm stats ========
  {
    int p = tid & 63, seg = tid >> 6;
    float s = 0.f, s2 = 0.f;
    for (int c = seg * 24; c < seg * 24 + 24; ++c) {
      float ov = bf2f(osh[c * 64 + p]);
      s += ov; s2 += ov * ov;
    }
    part[seg * 64 + p] = make_float2(s, s2);
  }
  __syncthreads();

  // ---- v-branch phases ----
  auto B1v = [&](int ch) {
    unsigned short* hb = hid + (ch & 1) * 12 * HID_STR;
    short8 av0 = *(const short8*)(wv1 + ((ch * 16 + ln) * 64 + quad * 8));
    short8 av1 = *(const short8*)(wv1 + ((ch * 16 + ln) * 64 + 32 + quad * 8));
    float bvv[4];
    #pragma unroll
    for (int r = 0; r < 4; ++r) {
      int row = quad * 4 + r;
      bvv[r] = (row < 12) ? bh[192 + ch * 12 + row] : 0.f;
    }
    for (int nt = wv; nt < 13; nt += 4) {
      int p = nt * 16 + ln;
      int rr = p / ROWS, cc = p - rr * ROWS;
      int gr = h - 1 + rr, gc = w0 - 1 + cc;
      bool pv = (rr < 3) && (cc < 66) && (gr >= 0) && (gr < H_) && (gc >= 0) && (gc < W_);
      const unsigned short* bp = xs_t + p * XT_STR + quad * 8;
      U128 b0, b1;
      b0.u[0] = *(const unsigned long long*)(bp);
      b0.u[1] = *(const unsigned long long*)(bp + 4);
      b1.u[0] = *(const unsigned long long*)(bp + 32);
      b1.u[1] = *(const unsigned long long*)(bp + 36);
      floatx4 acc = {bvv[0], bvv[1], bvv[2], bvv[3]};
      acc = __builtin_amdgcn_mfma_f32_16x16x32_bf16(av0, b0.s, acc, 0, 0, 0);
      acc = __builtin_amdgcn_mfma_f32_16x16x32_bf16(av1, b1.s, acc, 0, 0, 0);
      if (quad < 3 && rr < 3) {
        #pragma unroll
        for (int r = 0; r < 4; ++r)
          hb[(quad * 4 + r) * HID_STR + rr * HROW + cc] = pv ? f2bf(acc[r]) : (unsigned short)0;
      }
    }
  };

  auto B2vEpi = [&](int ch) {
    if (tid < 96) {
      const unsigned short* hb = hid + (ch & 1) * 12 * HID_STR;
      unsigned short* avp = (((ch >> 1) & 1) ? avpB : avpA);
      int lc = tid % 12, pg = tid / 12, p0 = pg * 8;
      int c2 = ch * 12 + lc, c6 = 192 + c2;
      const float* wd = wdw + c6 * 9;
      float bb = bdw[c6];
      float a8[8];
      #pragma unroll
      for (int t = 0; t < 8; ++t) a8[t] = bb;
      const unsigned short* base = hb + lc * HID_STR + p0;
      #pragma unroll
      for (int di = 0; di < 3; ++di) {
        const unsigned short* hrow = base + di * HROW;
        U128 hv;
        hv.u[0] = *(const unsigned long long*)(hrow);
        hv.u[1] = *(const unsigned long long*)(hrow + 4);
        unsigned int ex = *(const unsigned int*)(hrow + 8);
        float hf[10];
        #pragma unroll
        for (int t = 0; t < 4; ++t) hf[t] = bf2f((unsigned short)(hv.u[0] >> (16 * t)));
        #pragma unroll
        for (int t = 0; t < 4; ++t) hf[4 + t] = bf2f((unsigned short)(hv.u[1] >> (16 * t)));
        hf[8] = bf2f((unsigned short)ex);
        hf[9] = bf2f((unsigned short)(ex >> 16));
        #pragma unroll
        for (int dj = 0; dj < 3; ++dj) {
          float w = wd[di * 3 + dj];
          #pragma unroll
          for (int t = 0; t < 8; ++t) a8[t] += w * hf[t + dj];
        }
      }
      float gv = gam[c2], bev = bet[c2];
      #pragma unroll
      for (int t = 0; t < 8; ++t) {
        int p = p0 + t;
        float o = bf2f(osh[c2 * 64 + p]);
        float a = ((o - mu[p]) * rs[p] * gv + bev) * a8[t];
        avp[p * 24 + (ch & 1) * 12 + lc] = f2bf(a);
      }
    }
  };

  floatx4 oacc[3];
  #pragma unroll
  for (int mt = 0; mt < 3; ++mt)
    #pragma unroll
    for (int r = 0; r < 4; ++r) oacc[mt][r] = bo[mt * 16 + quad * 4 + r];

  auto MFMAacc = [&](int pr) {
    const unsigned short* avp = ((pr & 1) ? avpB : avpA);
    const unsigned short* bp = avp + (wv * 16 + ln) * 24 + quad * 8;
    U128 bfr;
    bfr.u[0] = *(const unsigned long long*)(bp);   // k 24..31: next-row data (or
    bfr.u[1] = *(const unsigned long long*)(bp + 4);  // zeroed/finite tail) * zero-A = 0
    #pragma unroll
    for (int mt = 0; mt < 3; ++mt) {
      short8 af = *(const short8*)(w2p + ((pr * 48 + mt * 16 + ln) * 32 + quad * 8));
      oacc[mt] = __builtin_amdgcn_mfma_f32_16x16x32_bf16(af, bfr.s, oacc[mt], 0, 0, 0);
    }
  };

  // LN finalize + v prologue in one region (part in qs-region, B1v writes hid)
  if (tid < 64) {
    float s = 0.f, s2 = 0.f;
    #pragma unroll
    for (int seg = 0; seg < 4; ++seg) {
      float2 pr2 = part[seg * 64 + tid];
      s += pr2.x; s2 += pr2.y;
    }
    float m = s * (1.f / 96.f);
    float var = s2 * (1.f / 96.f) - m * m;
    mu[tid] = m;
    rs[tid] = rsqrtf(var + 1e-5f);
  } else if (tid == 64) {
    // R5 FIX: zero avpA's 16-byte over-read tail (stale fp32 qs bits can decode
    // as bf16 NaN; 0*NaN = NaN would poison oacc at pixel w0+63).
    *(unsigned long long*)(avpA + 64 * 24)     = 0ull;
    *(unsigned long long*)(avpA + 64 * 24 + 4) = 0ull;
  }
  B1v(0);
  __syncthreads();

  // ======== pipelined v loop ========
  for (int ch = 0; ch < 8; ++ch) {
    if (ch < 7) B1v(ch + 1);
    if (ch >= 2 && (ch & 1) == 0) MFMAacc((ch >> 1) - 1);  // reads other avp buf
    B2vEpi(ch);
    __syncthreads();
  }
  MFMAacc(3);

  // ---- store y ----
  #pragma unroll
  for (int mt = 0; mt < 3; ++mt)
    #pragma unroll
    for (int r = 0; r < 4; ++r) {
      int co = mt * 16 + quad * 4 + r;
      y[(((b * C_) + co) * H_ + h) * W_ + w0 + wv * 16 + ln] = oacc[mt][r];
    }
}

extern "C" void kernel_launch(void* const* d_in, const int* in_sizes, int n_in,
                              void* d_out, int out_size, void* d_ws, size_t ws_size,
                              hipStream_t stream) {
  const float* x   = (const float*)d_in[0];
  const float* wh  = (const float*)d_in[1];
  const float* bh  = (const float*)d_in[2];
  const float* wdw = (const float*)d_in[3];
  const float* bdw = (const float*)d_in[4];
  const float* g   = (const float*)d_in[5];
  const float* be  = (const float*)d_in[6];
  const float* wo  = (const float*)d_in[7];
  const float* bo  = (const float*)d_in[8];
  float* y = (float*)d_out;
  unsigned short* ws = (unsigned short*)d_ws;   // 30720 ushorts

  fsas_prep<<<dim3(120), 256, 0, stream>>>(wh, wo, ws);
  dim3 grid(4, H_, B_);
  fsas_fused<<<grid, 256, 0, stream>>>(x, bh, wdw, bdw, g, be, bo, ws, y);
}